// Round 5
// baseline (331.777 us; speedup 1.0000x reference)
//
#include <hip/hip_runtime.h>
#include <hip/hip_bf16.h>

#define B_ROWS 8192
#define D_DIM  2048
#define C_DIM  1000
#define C_PAD  1024

#define EPS32   1.1920928955078125e-07f
// GAMMA = 1/exp(100) ~ 3.7e-44. GAMMA*rex ~ 1e-40 << ulp(h3~6.9) ~ 4.8e-7,
// so loss == mean(h3) exactly in fp32. rex pipeline deleted (round 5).
// Rounds 7-9 (fused GEMM A-staging) REVERTED: reg-staged fp32 A pinned MfmaUtil
// at ~11% across 3 schedules (113-125us) vs unfused pair at ~103us. Round 10:
// round-0 structure + (a) fuse_z contiguous-slab ILP-8, (b) finalize folded
// into rownorm via atomicAdd.

typedef __attribute__((ext_vector_type(8))) short short8;   // 8 bf16 = 4 VGPRs
typedef __attribute__((ext_vector_type(4))) float f32x4;    // MFMA accumulator

#define GLOAD_LDS16(gptr, lptr) \
  __builtin_amdgcn_global_load_lds((const __attribute__((address_space(1))) void*)(gptr), \
                                   (__attribute__((address_space(3))) void*)(lptr), 16, 0, 0)

__device__ inline unsigned short f2bf(float x) {
  union { __hip_bfloat16 b; unsigned short u; } cv;
  cv.b = __float2bfloat16(x);
  return cv.u;
}

__device__ inline float wave_red(float v) {
#pragma unroll
  for (int off = 32; off > 0; off >>= 1) v += __shfl_down(v, off, 64);
  return v;
}

// ---- B+P merged (round-10 layout):
//   blocks [0,2048):      z_bf[i] = bf16(feature[i]+eps[i]). Each block owns a
//                         CONTIGUOUS 2048-float4 slab per stream; thread does 8
//                         float4-pairs at 4KB stride within the slab (16 loads in
//                         flight, page-local — round-1's 8MB strides were the bug).
//   blocks [2048,2176):   cast cls_w [1000,2048] -> bf16 padded [1024,2048],
//                         same contiguous ILP-8 pattern.
#define NBZ 2048
__global__ __launch_bounds__(256) void fuse_z(const float4* __restrict__ f4,
                                              const float4* __restrict__ e4,
                                              uint2* __restrict__ z,
                                              const float* __restrict__ cls_w,
                                              __hip_bfloat16* __restrict__ clsw_bf,
                                              float* __restrict__ out_loss) {
  int bid = blockIdx.x, tid = threadIdx.x;
  if (bid == 0 && tid == 0) out_loss[0] = 0.f;   // rownorm accumulates into this
  if (bid < NBZ) {
    int base = bid * 2048 + tid;                 // slab: [bid*2048, bid*2048+2048)
    float4 f[8], e[8];
#pragma unroll
    for (int j = 0; j < 8; ++j) {
      f[j] = f4[base + j * 256];
      e[j] = e4[base + j * 256];
    }
#pragma unroll
    for (int j = 0; j < 8; ++j) {
      union { unsigned short u[4]; uint2 v; } pz;
      pz.u[0] = f2bf(f[j].x + e[j].x);
      pz.u[1] = f2bf(f[j].y + e[j].y);
      pz.u[2] = f2bf(f[j].z + e[j].z);
      pz.u[3] = f2bf(f[j].w + e[j].w);
      z[base + j * 256] = pz.v;
    }
  } else {
    int k0 = (bid - NBZ) * 2048 + tid;           // 16B-chunk index in [0, 262144)
#pragma unroll
    for (int j = 0; j < 8; ++j) {
      int k = k0 + j * 256;
      int row = k >> 8;                           // 256 chunks per 2048-elem row
      int col = (k & 255) * 8;
      union { unsigned short u[8]; uint4 v; } pk;
      if (row < C_DIM) {
        const float* src = cls_w + (size_t)row * D_DIM + col;
        float4 a = *(const float4*)src;
        float4 b = *(const float4*)(src + 4);
        pk.u[0] = f2bf(a.x); pk.u[1] = f2bf(a.y); pk.u[2] = f2bf(a.z); pk.u[3] = f2bf(a.w);
        pk.u[4] = f2bf(b.x); pk.u[5] = f2bf(b.y); pk.u[6] = f2bf(b.z); pk.u[7] = f2bf(b.w);
      } else {
#pragma unroll
        for (int i2 = 0; i2 < 8; ++i2) pk.u[i2] = 0;
      }
      *(uint4*)((unsigned short*)clsw_bf + (size_t)k * 8) = pk.v;
    }
  }
}

// ---- C: probs_raw = z @ cls_w^T + cls_b   (round-0 structure, proven ~48us)
// 128x128 tile, BK=64, 4 waves x (4x4) 16x16x32 MFMA.
// LDS layout XOR-swizzled: 16B chunk (row, cc) lives at slot row*8 + (cc ^ (row&7)).
__global__ __launch_bounds__(256) void gemm_bt(const __hip_bfloat16* __restrict__ A,
                                               const __hip_bfloat16* __restrict__ Bt,
                                               const float* __restrict__ cls_b,
                                               float* __restrict__ out) {
  __shared__ __align__(16) __hip_bfloat16 sA[128 * 64];
  __shared__ __align__(16) __hip_bfloat16 sB[128 * 64];
  const int tid = threadIdx.x;
  const int m0 = blockIdx.x * 128;
  const int n0 = blockIdx.y * 128;
  const int w = tid >> 6, lane = tid & 63;
  const int wm = (w & 1) * 64, wn = (w >> 1) * 64;
  const int l15 = lane & 15, quad = lane >> 4;

  f32x4 acc[4][4] = {};

  for (int k0 = 0; k0 < D_DIM; k0 += 64) {
#pragma unroll
    for (int i = 0; i < 4; ++i) {
      int j = i * 256 + tid;          // LDS slot: 1024 chunks of 16B per 128x64 tile
      int row = j >> 3;
      int cc = (j & 7) ^ (row & 7);   // inverse of the swizzle (XOR is an involution)
      const __hip_bfloat16* srcA = A + (size_t)(m0 + row) * D_DIM + k0 + cc * 8;
      const __hip_bfloat16* srcB = Bt + (size_t)(n0 + row) * D_DIM + k0 + cc * 8;
      GLOAD_LDS16(srcA, &sA[j * 8]);
      GLOAD_LDS16(srcB, &sB[j * 8]);
    }
    __syncthreads();
#pragma unroll
    for (int kk = 0; kk < 64; kk += 32) {
      const int ccr = (kk >> 3) + quad;   // which 8-elem chunk along K
      short8 af[4], bfr[4];
#pragma unroll
      for (int i = 0; i < 4; ++i) {
        int r = wm + i * 16 + l15;
        af[i] = *(const short8*)&sA[(r * 8 + (ccr ^ (r & 7))) * 8];
      }
#pragma unroll
      for (int jn = 0; jn < 4; ++jn) {
        int r = wn + jn * 16 + l15;
        bfr[jn] = *(const short8*)&sB[(r * 8 + (ccr ^ (r & 7))) * 8];
      }
#pragma unroll
      for (int i = 0; i < 4; ++i)
#pragma unroll
        for (int jn = 0; jn < 4; ++jn)
          acc[i][jn] = __builtin_amdgcn_mfma_f32_16x16x32_bf16(af[i], bfr[jn], acc[i][jn], 0, 0, 0);
    }
    __syncthreads();
  }

  // epilogue: C/D layout col=lane&15, row=quad*4+reg  (m89-verified)
#pragma unroll
  for (int i = 0; i < 4; ++i) {
    int row = m0 + wm + i * 16 + quad * 4;
#pragma unroll
    for (int jn = 0; jn < 4; ++jn) {
      int col = n0 + wn + jn * 16 + l15;
      if (col < C_DIM) {
        float bias = cls_b[col];
#pragma unroll
        for (int r = 0; r < 4; ++r)
          out[(size_t)(row + r) * C_DIM + col] = acc[i][jn][r] + bias;
      }
    }
  }
}

// ---- D: wave-autonomous per-row normalize+clamp+log. One wave per row; lane
// owns 16 cols as 4 float4 chunks. Target lane atomicAdds -log(p_t)/B into
// out_loss (finalize kernel deleted, round 10).
__global__ __launch_bounds__(256) void rownorm(float* __restrict__ out,
                                               const int* __restrict__ target,
                                               float* __restrict__ out_loss) {
  int b = blockIdx.x * 4 + (threadIdx.x >> 6);
  int lane = threadIdx.x & 63;
  float* row = out + (size_t)b * C_DIM;

  float v[16];
  float s = 0.f;
#pragma unroll
  for (int k = 0; k < 4; ++k) {
    int c = k * 256 + lane * 4;
    if (c + 3 < C_DIM) {
      float4 f = *(const float4*)(row + c);
      v[k * 4 + 0] = f.x; v[k * 4 + 1] = f.y; v[k * 4 + 2] = f.z; v[k * 4 + 3] = f.w;
    } else {
#pragma unroll
      for (int i = 0; i < 4; ++i) v[k * 4 + i] = (c + i < C_DIM) ? row[c + i] : 0.f;
    }
    s += v[k * 4 + 0] + v[k * 4 + 1] + v[k * 4 + 2] + v[k * 4 + 3];
  }
  s = wave_red(s);
  float inv = 1.0f / __shfl(s, 0, 64);
  int t = target[b];

#pragma unroll
  for (int k = 0; k < 4; ++k) {
    int c = k * 256 + lane * 4;
    float lg[4];
#pragma unroll
    for (int i = 0; i < 4; ++i) {
      float p = v[k * 4 + i] * inv;
      p = fminf(fmaxf(p, EPS32), 1.0f - EPS32);
      lg[i] = __logf(p);
      if (c + i == t) atomicAdd(out_loss, -lg[i] * (1.0f / B_ROWS));
    }
    if (c + 3 < C_DIM) {
      *(float4*)(row + c) = make_float4(lg[0], lg[1], lg[2], lg[3]);
    } else {
#pragma unroll
      for (int i = 0; i < 4; ++i) if (c + i < C_DIM) row[c + i] = lg[i];
    }
  }
}

extern "C" void kernel_launch(void* const* d_in, const int* in_sizes, int n_in,
                              void* d_out, int out_size, void* d_ws, size_t ws_size,
                              hipStream_t stream) {
  const float* feature = (const float*)d_in[0];
  const float* cls_w   = (const float*)d_in[3];
  const float* cls_b   = (const float*)d_in[4];
  const float* eps     = (const float*)d_in[5];
  const int*   target  = (const int*)d_in[6];
  float* out = (float*)d_out;
  float* out_loss = out + (size_t)B_ROWS * C_DIM;

  char* ws = (char*)d_ws;
  __hip_bfloat16* z_bf    = (__hip_bfloat16*)ws;                // 33554432 B
  __hip_bfloat16* clsw_bf = (__hip_bfloat16*)(ws + 33554432);   //  4194304 B

  fuse_z<<<dim3(NBZ + 128), 256, 0, stream>>>((const float4*)feature, (const float4*)eps,
                                              (uint2*)z_bf, cls_w, clsw_bf, out_loss);
  gemm_bt<<<dim3(B_ROWS / 128, C_PAD / 128), 256, 0, stream>>>(z_bf, clsw_bf, cls_b, out);
  rownorm<<<dim3(B_ROWS / 4), 256, 0, stream>>>(out, target, out_loss);
}

// Round 6
// 260.155 us; speedup vs baseline: 1.2753x; 1.2753x over previous
//
#include <hip/hip_runtime.h>
#include <hip/hip_bf16.h>

#define B_ROWS 8192
#define D_DIM  2048
#define C_DIM  1000
#define C_PAD  1024

#define EPS32   1.1920928955078125e-07f
// GAMMA = 1/exp(100) ~ 3.7e-44. GAMMA*rex ~ 1e-40 << ulp(h3~6.9) ~ 4.8e-7,
// so loss == mean(h3) exactly in fp32. rex pipeline deleted (round 5).
// Round 11 (megakernel): BM=32 x BN=1024(full padded row) x BK=32, 256 blocks
// (1/CU), 512 threads. One block owns a full output row-panel, so:
//  - bf16(feature+eps) fuses into A-staging with ZERO replication (A read once);
//    z_bf intermediate deleted.
//  - normalize+clamp+log+loss fuse into the epilogue (full row in acc);
//    rownorm + finalize kernels deleted; out written once, never re-read.
//  - B (4MB bf16) streams from per-XCD L2 (32 CUs share it): ~1GB L2 ~ 30us floor.
// Round-5 lesson: loss accumulation = 256 block atomics (8192 single-address
// atomics cost ~60us of serialization).

typedef __attribute__((ext_vector_type(8))) short short8;   // 8 bf16 = 4 VGPRs
typedef __attribute__((ext_vector_type(4))) float f32x4;    // MFMA accumulator

#define GLOAD_LDS16(gptr, lptr) \
  __builtin_amdgcn_global_load_lds((const __attribute__((address_space(1))) void*)(gptr), \
                                   (__attribute__((address_space(3))) void*)(lptr), 16, 0, 0)

__device__ inline unsigned short f2bf(float x) {
  union { __hip_bfloat16 b; unsigned short u; } cv;
  cv.b = __float2bfloat16(x);
  return cv.u;
}

__device__ inline float wave_red(float v) {
#pragma unroll
  for (int off = 32; off > 0; off >>= 1) v += __shfl_down(v, off, 64);
  return v;
}

// ---- P: cast cls_w [1000,2048] fp32 -> bf16 padded [1024,2048]; zero out_loss.
__global__ __launch_bounds__(256) void cast_w(const float* __restrict__ cls_w,
                                              __hip_bfloat16* __restrict__ clsw_bf,
                                              float* __restrict__ out_loss) {
  if (blockIdx.x == 0 && threadIdx.x == 0) out_loss[0] = 0.f;
  int j = (blockIdx.x * 256 + threadIdx.x) * 8;   // elem idx in [1024][2048]
  int row = j >> 11;
  int col = j & 2047;
  union { unsigned short u[8]; uint4 v; } pk;
  if (row < C_DIM) {
    const float* src = cls_w + (size_t)row * D_DIM + col;
    float4 a = *(const float4*)src;
    float4 b = *(const float4*)(src + 4);
    pk.u[0] = f2bf(a.x); pk.u[1] = f2bf(a.y); pk.u[2] = f2bf(a.z); pk.u[3] = f2bf(a.w);
    pk.u[4] = f2bf(b.x); pk.u[5] = f2bf(b.y); pk.u[6] = f2bf(b.z); pk.u[7] = f2bf(b.w);
  } else {
#pragma unroll
    for (int i2 = 0; i2 < 8; ++i2) pk.u[i2] = 0;
  }
  *(uint4*)((unsigned short*)clsw_bf + j) = pk.v;
}

// ---- Megakernel: logits + loss in one pass.
// 8 waves; wave w owns rows[0:32) x cols[w*128, w*128+128). acc[2][8] f32x4.
// LDS XOR-swizzle (4 chunks/row of 16B): chunk (row,cc) at slot row*4 + (cc^(row&3)).
// B staged via global_load_lds (linear dest = uniform+lane*16, swizzle on SOURCE);
// A reg-staged fp32 f+e -> add -> cvt -> ds_write_b128 (tid<128 only, 8KB/step).
__global__ __launch_bounds__(512, 2) void fused_all(const float* __restrict__ feature,
                                                    const float* __restrict__ eps,
                                                    const __hip_bfloat16* __restrict__ Bt,
                                                    const float* __restrict__ cls_b,
                                                    const int* __restrict__ target,
                                                    float* __restrict__ out,
                                                    float* __restrict__ out_loss) {
  __shared__ __align__(16) __hip_bfloat16 sB0[C_PAD * 32];   // 64 KB
  __shared__ __align__(16) __hip_bfloat16 sB1[C_PAD * 32];   // 64 KB
  __shared__ __align__(16) __hip_bfloat16 sA0[32 * 32];      //  2 KB
  __shared__ __align__(16) __hip_bfloat16 sA1[32 * 32];      //  2 KB
  __shared__ float red[32][8];
  __shared__ float red2[32];
  __shared__ float wred[8];

  const int tid = threadIdx.x;
  const int m0 = blockIdx.x * 32;
  const int w = tid >> 6, lane = tid & 63;
  const int l15 = lane & 15, quad = lane >> 4;
  const int wn = w * 128;

  // B staging geometry: 4096 16B-chunks per 1024x32 tile; 8 per thread.
  const __hip_bfloat16* Bb[8]; int slotB[8];
#pragma unroll
  for (int i = 0; i < 8; ++i) {
    int j = i * 512 + tid;
    int row = j >> 2;
    int cc = (j & 3) ^ (row & 3);       // pre-swizzled source (XOR involution)
    Bb[i] = Bt + (size_t)row * D_DIM + cc * 8;
    slotB[i] = j * 8;                    // elem offset (16B per chunk)
  }
  // A staging geometry: 128 chunks (32 rows x 4), tid<128 only.
  const float* Fp = feature; const float* Ep = eps; int slotA = 0;
  if (tid < 128) {
    int arow = tid >> 2;
    int ac = (tid & 3) ^ (arow & 3);
    Fp = feature + (size_t)(m0 + arow) * D_DIM + ac * 8;
    Ep = eps     + (size_t)(m0 + arow) * D_DIM + ac * 8;
    slotA = tid * 8;
  }

  f32x4 acc[2][8] = {};
  float4 f0, f1, e0, e1;

  auto LOADA = [&](int k0) {
    if (tid < 128) {
      f0 = *(const float4*)(Fp + k0);
      f1 = *(const float4*)(Fp + k0 + 4);
      e0 = *(const float4*)(Ep + k0);
      e1 = *(const float4*)(Ep + k0 + 4);
    }
  };
  auto WRITEA = [&](__hip_bfloat16* sA) {
    if (tid < 128) {
      union { unsigned short u[8]; uint4 v; } pk;
      pk.u[0] = f2bf(f0.x + e0.x); pk.u[1] = f2bf(f0.y + e0.y);
      pk.u[2] = f2bf(f0.z + e0.z); pk.u[3] = f2bf(f0.w + e0.w);
      pk.u[4] = f2bf(f1.x + e1.x); pk.u[5] = f2bf(f1.y + e1.y);
      pk.u[6] = f2bf(f1.z + e1.z); pk.u[7] = f2bf(f1.w + e1.w);
      *(uint4*)&sA[slotA] = pk.v;
    }
  };
  auto GLOADB = [&](__hip_bfloat16* sB, int k0) {
#pragma unroll
    for (int i = 0; i < 8; ++i) GLOAD_LDS16(Bb[i] + k0, &sB[slotB[i]]);
  };
  auto COMPUTE = [&](const __hip_bfloat16* sA, const __hip_bfloat16* sB) {
    const int ccr = quad;               // BK=32: chunk = quad (K = quad*8..+7)
    short8 af[2], bfr[8];
#pragma unroll
    for (int i = 0; i < 2; ++i) {
      int r = i * 16 + l15;
      af[i] = *(const short8*)&sA[(r * 4 + (ccr ^ (r & 3))) * 8];
    }
#pragma unroll
    for (int jn = 0; jn < 8; ++jn) {
      int r = wn + jn * 16 + l15;
      bfr[jn] = *(const short8*)&sB[(r * 4 + (ccr ^ (r & 3))) * 8];
    }
#pragma unroll
    for (int i = 0; i < 2; ++i)
#pragma unroll
      for (int jn = 0; jn < 8; ++jn)
        acc[i][jn] = __builtin_amdgcn_mfma_f32_16x16x32_bf16(af[i], bfr[jn], acc[i][jn], 0, 0, 0);
  };

  // prologue
  LOADA(0);
  GLOADB(sB0, 0);
  WRITEA(sA0);
  __syncthreads();

  __hip_bfloat16 *cA = sA0, *cB = sB0, *nA = sA1, *nB = sB1;
  for (int t = 0; t < 64; ++t) {
    const int kn = (t + 1) * 32;
    const bool pf = t < 63;
    if (pf) {
      LOADA(kn);          // tiny HBM A(t+1) — hides under COMPUTE
      GLOADB(nB, kn);     // 64KB L2->LDS DMA — drains at the barrier
    }
    COMPUTE(cA, cB);
    if (pf) WRITEA(nA);
    __syncthreads();
    __hip_bfloat16* tmp;
    tmp = cA; cA = nA; nA = tmp;
    tmp = cB; cB = nB; nB = tmp;
  }

  // ---- epilogue: bias -> row-sum -> normalize/clamp/log -> store + loss.
  // acc[i][jn][r] maps to row = i*16 + quad*4 + r, col = wn + jn*16 + l15 (m89).
  float bias[8]; int bcol[8];
#pragma unroll
  for (int jn = 0; jn < 8; ++jn) {
    int c = wn + jn * 16 + l15;
    bcol[jn] = c;
    bias[jn] = (c < C_DIM) ? cls_b[c] : 0.f;   // pad cols: acc=0 (B pad rows are 0)
  }
#pragma unroll
  for (int i = 0; i < 2; ++i)
#pragma unroll
    for (int jn = 0; jn < 8; ++jn)
#pragma unroll
      for (int r = 0; r < 4; ++r) acc[i][jn][r] += bias[jn];

  // per-lane partial row sums over its 8 cols, then reduce across the 16 l15 lanes
#pragma unroll
  for (int i = 0; i < 2; ++i)
#pragma unroll
    for (int r = 0; r < 4; ++r) {
      float s = 0.f;
#pragma unroll
      for (int jn = 0; jn < 8; ++jn) s += acc[i][jn][r];
#pragma unroll
      for (int off = 1; off < 16; off <<= 1) s += __shfl_xor(s, off, 64);
      if (l15 == 0) red[i * 16 + quad * 4 + r][w] = s;
    }
  __syncthreads();
  if (tid < 32) {
    float s = 0.f;
#pragma unroll
    for (int k = 0; k < 8; ++k) s += red[tid][k];
    red2[tid] = 1.0f / s;
  }
  __syncthreads();

  float lsum = 0.f;
#pragma unroll
  for (int i = 0; i < 2; ++i)
#pragma unroll
    for (int r = 0; r < 4; ++r) {
      int R = i * 16 + quad * 4 + r;
      float inv = red2[R];
      int tr = target[m0 + R];
      float* orow = out + (size_t)(m0 + R) * C_DIM;
#pragma unroll
      for (int jn = 0; jn < 8; ++jn) {
        int c = bcol[jn];
        if (c < C_DIM) {
          float p = acc[i][jn][r] * inv;
          p = fminf(fmaxf(p, EPS32), 1.0f - EPS32);
          float lg = __logf(p);
          orow[c] = lg;
          if (c == tr) lsum -= lg;
        }
      }
    }
  lsum = wave_red(lsum);
  if (lane == 0) wred[w] = lsum;
  __syncthreads();
  if (tid == 0) {
    float s = 0.f;
#pragma unroll
    for (int k = 0; k < 8; ++k) s += wred[k];
    atomicAdd(out_loss, s * (1.0f / B_ROWS));   // 256 atomics total
  }
}

extern "C" void kernel_launch(void* const* d_in, const int* in_sizes, int n_in,
                              void* d_out, int out_size, void* d_ws, size_t ws_size,
                              hipStream_t stream) {
  const float* feature = (const float*)d_in[0];
  const float* cls_w   = (const float*)d_in[3];
  const float* cls_b   = (const float*)d_in[4];
  const float* eps     = (const float*)d_in[5];
  const int*   target  = (const int*)d_in[6];
  float* out = (float*)d_out;
  float* out_loss = out + (size_t)B_ROWS * C_DIM;

  char* ws = (char*)d_ws;
  __hip_bfloat16* clsw_bf = (__hip_bfloat16*)ws;               // 4194304 B

  cast_w<<<dim3(1024), 256, 0, stream>>>(cls_w, clsw_bf, out_loss);
  fused_all<<<dim3(B_ROWS / 32), 512, 0, stream>>>(feature, eps, clsw_bf, cls_b,
                                                   target, out, out_loss);
}

// Round 7
// 232.547 us; speedup vs baseline: 1.4267x; 1.1187x over previous
//
#include <hip/hip_runtime.h>
#include <hip/hip_bf16.h>

#define B_ROWS 8192
#define D_DIM  2048
#define C_DIM  1000
#define C_PAD  1024

#define EPS32   1.1920928955078125e-07f
// GAMMA = 1/exp(100) ~ 3.7e-44. GAMMA*rex ~ 1e-40 << ulp(h3~6.9) ~ 4.8e-7,
// so loss == mean(h3) exactly in fp32. rex pipeline deleted (round 5).
// Round 11 (megakernel) ABANDONED: BM=32 means every CU ingests all 4MB of B
// (1GB device-wide); per-K-step 64KB DMA >> 150cy compute, 1 blk/CU, no LDS
// left to pipeline. Measured 136us vs ~35us floor. Also: atomic-to-out_loss
// versions (r5, r6) carry ~+50us unexplained bench overhead — avoid atomics.
// Round 12: round-0 proven fuse_z/gemm_bt restored verbatim; rownorm rewritten
// 4 rows/wave (ILP-16 loads, amortized serial reduce); finalize 1024-thr ILP-8.

typedef __attribute__((ext_vector_type(8))) short short8;   // 8 bf16 = 4 VGPRs
typedef __attribute__((ext_vector_type(4))) float f32x4;    // MFMA accumulator

#define GLOAD_LDS16(gptr, lptr) \
  __builtin_amdgcn_global_load_lds((const __attribute__((address_space(1))) void*)(gptr), \
                                   (__attribute__((address_space(3))) void*)(lptr), 16, 0, 0)

__device__ inline unsigned short f2bf(float x) {
  union { __hip_bfloat16 b; unsigned short u; } cv;
  cv.b = __float2bfloat16(x);
  return cv.u;
}

__device__ inline float wave_red(float v) {
#pragma unroll
  for (int off = 32; off > 0; off >>= 1) v += __shfl_down(v, off, 64);
  return v;
}

// ---- B+P merged (round-0 proven, 54.6us):
//   blocks [0,16384):      z_bf[i] = bf16(feature[i] + eps[i]), one float4-pair
//                          per thread (max TLP: ~32 waves/CU, 2 loads each).
//   blocks [16384,17408):  cast cls_w [1000,2048] -> bf16 padded [1024,2048].
__global__ __launch_bounds__(256) void fuse_z(const float4* __restrict__ f4,
                                              const float4* __restrict__ e4,
                                              uint2* __restrict__ z,
                                              const float* __restrict__ cls_w,
                                              __hip_bfloat16* __restrict__ clsw_bf) {
  int bid = blockIdx.x;
  if (bid < 16384) {
    int i = bid * 256 + threadIdx.x;
    float4 f = f4[i];
    float4 e = e4[i];
    union { unsigned short u[4]; uint2 v; } pz;
    pz.u[0] = f2bf(f.x + e.x);
    pz.u[1] = f2bf(f.y + e.y);
    pz.u[2] = f2bf(f.z + e.z);
    pz.u[3] = f2bf(f.w + e.w);
    z[i] = pz.v;
  } else {
    int j = ((bid - 16384) * 256 + threadIdx.x) * 8;   // elem idx in [1024][2048]
    int row = j >> 11;
    int col = j & 2047;
    union { unsigned short u[8]; uint4 v; } pk;
    if (row < C_DIM) {
      const float* src = cls_w + (size_t)row * D_DIM + col;
#pragma unroll
      for (int i2 = 0; i2 < 8; ++i2) pk.u[i2] = f2bf(src[i2]);
    } else {
#pragma unroll
      for (int i2 = 0; i2 < 8; ++i2) pk.u[i2] = 0;
    }
    *(uint4*)((unsigned short*)clsw_bf + j) = pk.v;
  }
}

// ---- C: probs_raw = z @ cls_w^T + cls_b   (round-0 proven)
// 128x128 tile, BK=64, 4 waves x (4x4) 16x16x32 MFMA.
// LDS layout XOR-swizzled: 16B chunk (row, cc) lives at slot row*8 + (cc ^ (row&7)).
__global__ __launch_bounds__(256) void gemm_bt(const __hip_bfloat16* __restrict__ A,
                                               const __hip_bfloat16* __restrict__ Bt,
                                               const float* __restrict__ cls_b,
                                               float* __restrict__ out) {
  __shared__ __align__(16) __hip_bfloat16 sA[128 * 64];
  __shared__ __align__(16) __hip_bfloat16 sB[128 * 64];
  const int tid = threadIdx.x;
  const int m0 = blockIdx.x * 128;
  const int n0 = blockIdx.y * 128;
  const int w = tid >> 6, lane = tid & 63;
  const int wm = (w & 1) * 64, wn = (w >> 1) * 64;
  const int l15 = lane & 15, quad = lane >> 4;

  f32x4 acc[4][4] = {};

  for (int k0 = 0; k0 < D_DIM; k0 += 64) {
#pragma unroll
    for (int i = 0; i < 4; ++i) {
      int j = i * 256 + tid;          // LDS slot: 1024 chunks of 16B per 128x64 tile
      int row = j >> 3;
      int cc = (j & 7) ^ (row & 7);   // inverse of the swizzle (XOR is an involution)
      const __hip_bfloat16* srcA = A + (size_t)(m0 + row) * D_DIM + k0 + cc * 8;
      const __hip_bfloat16* srcB = Bt + (size_t)(n0 + row) * D_DIM + k0 + cc * 8;
      GLOAD_LDS16(srcA, &sA[j * 8]);
      GLOAD_LDS16(srcB, &sB[j * 8]);
    }
    __syncthreads();
#pragma unroll
    for (int kk = 0; kk < 64; kk += 32) {
      const int ccr = (kk >> 3) + quad;   // which 8-elem chunk along K
      short8 af[4], bfr[4];
#pragma unroll
      for (int i = 0; i < 4; ++i) {
        int r = wm + i * 16 + l15;
        af[i] = *(const short8*)&sA[(r * 8 + (ccr ^ (r & 7))) * 8];
      }
#pragma unroll
      for (int jn = 0; jn < 4; ++jn) {
        int r = wn + jn * 16 + l15;
        bfr[jn] = *(const short8*)&sB[(r * 8 + (ccr ^ (r & 7))) * 8];
      }
#pragma unroll
      for (int i = 0; i < 4; ++i)
#pragma unroll
        for (int jn = 0; jn < 4; ++jn)
          acc[i][jn] = __builtin_amdgcn_mfma_f32_16x16x32_bf16(af[i], bfr[jn], acc[i][jn], 0, 0, 0);
    }
    __syncthreads();
  }

  // epilogue: C/D layout col=lane&15, row=quad*4+reg  (m89-verified)
#pragma unroll
  for (int i = 0; i < 4; ++i) {
    int row = m0 + wm + i * 16 + quad * 4;
#pragma unroll
    for (int jn = 0; jn < 4; ++jn) {
      int col = n0 + wn + jn * 16 + l15;
      if (col < C_DIM) {
        float bias = cls_b[col];
#pragma unroll
        for (int r = 0; r < 4; ++r)
          out[(size_t)(row + r) * C_DIM + col] = acc[i][jn][r] + bias;
      }
    }
  }
}

// ---- D: per-row normalize+clamp+log, 4 rows per wave (round 12).
// All 16 float4 loads issued before use (ILP-16); 4 independent reduce chains.
// Grid 512 blocks x 4 waves x 4 rows = 8192 rows.
__global__ __launch_bounds__(256) void rownorm(float* __restrict__ out,
                                               const int* __restrict__ target,
                                               float* __restrict__ rowloss) {
  const int wv = threadIdx.x >> 6, lane = threadIdx.x & 63;
  const int r0 = blockIdx.x * 16 + wv * 4;

  float v[4][16];
#pragma unroll
  for (int rr = 0; rr < 4; ++rr) {
    const float* row = out + (size_t)(r0 + rr) * C_DIM;
#pragma unroll
    for (int k = 0; k < 4; ++k) {
      int c = k * 256 + lane * 4;
      if (c + 3 < C_DIM) {
        float4 f = *(const float4*)(row + c);
        v[rr][k * 4 + 0] = f.x; v[rr][k * 4 + 1] = f.y;
        v[rr][k * 4 + 2] = f.z; v[rr][k * 4 + 3] = f.w;
      } else {
#pragma unroll
        for (int i = 0; i < 4; ++i) v[rr][k * 4 + i] = (c + i < C_DIM) ? row[c + i] : 0.f;
      }
    }
  }

  float s[4];
#pragma unroll
  for (int rr = 0; rr < 4; ++rr) {
    float a = 0.f;
#pragma unroll
    for (int k = 0; k < 16; ++k) a += v[rr][k];
    s[rr] = a;
  }
#pragma unroll
  for (int rr = 0; rr < 4; ++rr) {
#pragma unroll
    for (int off = 32; off > 0; off >>= 1) s[rr] += __shfl_down(s[rr], off, 64);
    s[rr] = __shfl(s[rr], 0, 64);
  }

  int tg[4];
#pragma unroll
  for (int rr = 0; rr < 4; ++rr) tg[rr] = target[r0 + rr];

#pragma unroll
  for (int rr = 0; rr < 4; ++rr) {
    float inv = 1.0f / s[rr];
    float* row = out + (size_t)(r0 + rr) * C_DIM;
#pragma unroll
    for (int k = 0; k < 4; ++k) {
      int c = k * 256 + lane * 4;
      float lg[4];
#pragma unroll
      for (int i = 0; i < 4; ++i) {
        float p = v[rr][k * 4 + i] * inv;
        p = fminf(fmaxf(p, EPS32), 1.0f - EPS32);
        lg[i] = __logf(p);
        if (c + i == tg[rr]) rowloss[r0 + rr] = -lg[i];
      }
      if (c + 3 < C_DIM) {
        *(float4*)(row + c) = make_float4(lg[0], lg[1], lg[2], lg[3]);
      } else {
#pragma unroll
        for (int i = 0; i < 4; ++i) if (c + i < C_DIM) row[c + i] = lg[i];
      }
    }
  }
}

// ---- E: loss = mean(rowloss). One 1024-thread block, ILP-8, plain store.
__global__ __launch_bounds__(1024) void finalize(const float* __restrict__ rowloss,
                                                 float* __restrict__ out_loss) {
  int tid = threadIdx.x;
  float a[8];
#pragma unroll
  for (int j = 0; j < 8; ++j) a[j] = rowloss[tid + j * 1024];
  float s = 0.f;
#pragma unroll
  for (int j = 0; j < 8; ++j) s += a[j];
  s = wave_red(s);
  __shared__ float sm[16];
  if ((tid & 63) == 0) sm[tid >> 6] = s;
  __syncthreads();
  if (tid == 0) {
    float t = 0.f;
#pragma unroll
    for (int k = 0; k < 16; ++k) t += sm[k];
    out_loss[0] = t * (1.0f / B_ROWS);
  }
}

extern "C" void kernel_launch(void* const* d_in, const int* in_sizes, int n_in,
                              void* d_out, int out_size, void* d_ws, size_t ws_size,
                              hipStream_t stream) {
  const float* feature = (const float*)d_in[0];
  const float* cls_w   = (const float*)d_in[3];
  const float* cls_b   = (const float*)d_in[4];
  const float* eps     = (const float*)d_in[5];
  const int*   target  = (const int*)d_in[6];
  float* out = (float*)d_out;
  float* out_loss = out + (size_t)B_ROWS * C_DIM;

  char* ws = (char*)d_ws;
  __hip_bfloat16* z_bf    = (__hip_bfloat16*)ws;                // 33554432 B
  __hip_bfloat16* clsw_bf = (__hip_bfloat16*)(ws + 33554432);   //  4194304 B
  float*          rowloss = (float*)(ws + 33554432 + 4194304);  //    32768 B

  fuse_z<<<dim3(16384 + 1024), 256, 0, stream>>>((const float4*)feature, (const float4*)eps,
                                                 (uint2*)z_bf, cls_w, clsw_bf);
  gemm_bt<<<dim3(B_ROWS / 128, C_PAD / 128), 256, 0, stream>>>(z_bf, clsw_bf, cls_b, out);
  rownorm<<<dim3(B_ROWS / 16), 256, 0, stream>>>(out, target, rowloss);
  finalize<<<dim3(1), 1024, 0, stream>>>(rowloss, out_loss);
}